// Round 4
// baseline (240.125 us; speedup 1.0000x reference)
//
#include <hip/hip_runtime.h>
#include <cstdint>
#include <cstddef>

typedef __bf16 bf16x8 __attribute__((ext_vector_type(8)));
typedef float f32x4 __attribute__((ext_vector_type(4)));
typedef unsigned int u32x2 __attribute__((ext_vector_type(2)));

#define MFMA16(a, b, c) __builtin_amdgcn_mfma_f32_16x16x32_bf16((a), (b), (c), 0, 0, 0)

static constexpr int CD = 128;
static constexpr int NTOK = 65536;
static constexpr float F_SCALE = 0.17677669529663688f;  // 1/sqrt(32)
static constexpr float F_LOG2E = 1.4426950408889634f;
static constexpr int PART = 4224;    // 4096 S + 128 Z floats per k1 block
static constexpr int NPARTS = 128;   // k1 blocks per batch

__device__ __forceinline__ unsigned pk2(float a, float b) {
  unsigned short ua = __builtin_bit_cast(unsigned short, (__bf16)a);
  unsigned short ub = __builtin_bit_cast(unsigned short, (__bf16)b);
  return (unsigned)ua | ((unsigned)ub << 16);
}

// Per-wave register stage of a [128 c][16 n] fp32 sub-strip.
// Instr u: rows u*32 + (lane>>2)*2 (A) and +1 (B), n-quad = lane&3.
// Per instr: 16 rows x 64B contiguous chunks (sector-aligned).
struct Frag { f32x4 A[4]; f32x4 B[4]; };

__device__ __forceinline__ Frag load_strip(const float* src, int lane) {
  Frag f;
#pragma unroll
  for (int u = 0; u < 4; ++u) {
    const float* p = src + (size_t)(u * 32 + (lane >> 2) * 2) * NTOK + (lane & 3) * 4;
    f.A[u] = *(const f32x4*)p;
    f.B[u] = *(const f32x4*)(p + NTOK);
  }
  return f;
}

// Pack c-pairs to bf16 and write T2 rows [16 n][128 c] bf16 at T2row (row n
// local 0..15), swizzle: phys_byte = logical_byte ^ ((n&7)<<4). 2-way banks.
__device__ __forceinline__ void pack_write(const Frag& f, char* T2row, int lane) {
#pragma unroll
  for (int u = 0; u < 4; ++u)
#pragma unroll
    for (int j = 0; j < 4; ++j) {
      int n = (lane & 3) * 4 + j;
      int cp = u * 16 + (lane >> 2);  // c-pair index, logical byte = 4*cp
      *(unsigned*)(T2row + n * 256 + ((cp * 4) ^ ((n & 7) << 4))) =
          pk2(f.A[u][j], f.B[u][j]);
    }
}

// ---------------- kernel 1: context -> S,Z partials ----------------
// grid 512 = 4 b x 128 chunks of 512 n. Block-cooperative: per 64-n strip all
// 4 waves stage 16 n each into shared T2 (double-buffered, ONE barrier/strip);
// wave w computes head w (all 64 n). E/V tiles + S-MFMA wave-private.
__global__ __launch_bounds__(256, 2) void k1_ctx(
    const float* __restrict__ ctx_in, const float* __restrict__ Wk,
    const float* __restrict__ Wv, float* __restrict__ S_part) {
  __shared__ char smem[64 * 1024];  // T2[2] 2x16KB | per-wave E 4K + V 4K
  const int tid = threadIdx.x;
  const int lane = tid & 63;
  const int w = tid >> 6;
  const int l15 = lane & 15;
  const int lg = lane >> 4;
  const int b = blockIdx.x >> 7;
  const int cb = blockIdx.x & 127;

  char* Eb = smem + 32 * 1024 + w * 8192;
  char* Vb = Eb + 4096;

  // Weight B-fragments for head w: col = weight row = w*32 + (m&1)*16 + l15,
  // k = c = ks*32 + lg*8 + e. m=0,1 -> Wk (prescaled by log2e); m=2,3 -> Wv.
  bf16x8 Wf[4][4];
#pragma unroll
  for (int m = 0; m < 4; ++m) {
    const float* Wp = (m < 2) ? Wk : Wv;
    const float sc = (m < 2) ? F_LOG2E : 1.0f;
    int row = w * 32 + (m & 1) * 16 + l15;
#pragma unroll
    for (int ks = 0; ks < 4; ++ks) {
      const float* p = Wp + row * CD + ks * 32 + lg * 8;
#pragma unroll
      for (int e = 0; e < 8; ++e) Wf[m][ks][e] = (__bf16)(p[e] * sc);
    }
  }

  f32x4 Sacc[2][2];
#pragma unroll
  for (int i = 0; i < 2; ++i)
#pragma unroll
    for (int j = 0; j < 2; ++j) Sacc[i][j] = f32x4{0.f, 0.f, 0.f, 0.f};
  float zacc[2] = {0.f, 0.f};

  // Wave w stages the n-sub-strip [w*16, w*16+16) of each 64-n strip.
  const float* src = ctx_in + (size_t)b * CD * NTOK + cb * 512 + w * 16;

  Frag f = load_strip(src, lane);
#pragma unroll
  for (int s = 0; s < 8; ++s) {
    Frag fn;
    if (s < 7) fn = load_strip(src + (s + 1) * 64, lane);  // prefetch under compute
    char* T2 = smem + (s & 1) * 16384;
    pack_write(f, T2 + w * 4096, lane);
    __syncthreads();  // T2[s&1] complete; also: all compute(s-1) reads done

    // projections: D[n][wrow], n = t*16 + lg*4 + r, wrow col = l15
    f32x4 acc[4][4];
#pragma unroll
    for (int m = 0; m < 4; ++m)
#pragma unroll
      for (int t = 0; t < 4; ++t) acc[m][t] = f32x4{0.f, 0.f, 0.f, 0.f};
#pragma unroll
    for (int ks = 0; ks < 4; ++ks) {
      bf16x8 At[4];
#pragma unroll
      for (int t = 0; t < 4; ++t)
        At[t] = *(const bf16x8*)(T2 + (t * 16 + l15) * 256 +
                                 ((ks * 64 + lg * 16) ^ ((l15 & 7) << 4)));
#pragma unroll
      for (int m = 0; m < 4; ++m)
#pragma unroll
        for (int t = 0; t < 4; ++t) acc[m][t] = MFMA16(At[t], Wf[m][ks], acc[m][t]);
    }

    // exp + packed E/V into wave-private [32 d][64 n] bf16 tiles (2-way swz)
#pragma unroll
    for (int m = 0; m < 2; ++m) {
      int d = m * 16 + l15;
      int dx = (d & 7) << 4;
#pragma unroll
      for (int t = 0; t < 4; ++t) {
        f32x4 a = acc[m][t];
        float e0 = __builtin_exp2f(a[0]), e1 = __builtin_exp2f(a[1]);
        float e2 = __builtin_exp2f(a[2]), e3 = __builtin_exp2f(a[3]);
        zacc[m] += (e0 + e1) + (e2 + e3);
        *(u32x2*)(Eb + d * 128 + ((t * 32 + lg * 8) ^ dx)) =
            u32x2{pk2(e0, e1), pk2(e2, e3)};
        f32x4 v = acc[m + 2][t];
        *(u32x2*)(Vb + d * 128 + ((t * 32 + lg * 8) ^ dx)) =
            u32x2{pk2(v[0], v[1]), pk2(v[2], v[3])};
      }
    }

    // S[d][e] += E[d][n] * V[e][n], K = 64 (wave-private, no barrier)
#pragma unroll
    for (int s2 = 0; s2 < 2; ++s2) {
      bf16x8 Ea[2], Vv[2];
#pragma unroll
      for (int md = 0; md < 2; ++md) {
        int d = md * 16 + l15;
        int off = d * 128 + ((s2 * 64 + lg * 16) ^ ((d & 7) << 4));
        Ea[md] = *(const bf16x8*)(Eb + off);
        Vv[md] = *(const bf16x8*)(Vb + off);
      }
#pragma unroll
      for (int md = 0; md < 2; ++md)
#pragma unroll
        for (int ne = 0; ne < 2; ++ne) Sacc[md][ne] = MFMA16(Ea[md], Vv[ne], Sacc[md][ne]);
    }
    if (s < 7) f = fn;
  }

  // Lane-linear partial writes (coalesced b128); mapping (used by k2b):
  // value (d = md*16+lg*4+r, e = ne*16+l15) at flat w*1024 + (md*2+ne)*256 + lane*4 + r
  float* outp = S_part + (size_t)blockIdx.x * PART;
#pragma unroll
  for (int md = 0; md < 2; ++md)
#pragma unroll
    for (int ne = 0; ne < 2; ++ne)
      *(f32x4*)(outp + w * 1024 + (md * 2 + ne) * 256 + lane * 4) = Sacc[md][ne];
#pragma unroll
  for (int m = 0; m < 2; ++m) {
    float z = zacc[m];
    z += __shfl_xor(z, 16, 64);
    z += __shfl_xor(z, 32, 64);
    if (lg == 0) outp[4096 + w * 32 + m * 16 + l15] = z;  // Z[h=w][d=m*16+l15]
  }
}

// ---------------- kernel 2a: reduce partials ----------------
__global__ void k2a_reduce(const float* __restrict__ S_part, float* __restrict__ S_red,
                           float* __restrict__ Z_red) {
  int bid = blockIdx.x;
  int b = bid / 33, bs = bid % 33;
  int tid = threadIdx.x;
  __shared__ float red[256];
  int e_loc = tid & 127, half = tid >> 7;
  const float* base =
      S_part + (size_t)b * NPARTS * PART + (bs < 32 ? bs * 128 + e_loc : 4096 + e_loc);
  float sum = 0.f;
  int h = NPARTS >> 1;
  for (int p = half * h; p < half * h + h; ++p) sum += base[(size_t)p * PART];
  red[tid] = sum;
  __syncthreads();
  if (tid < 128) {
    float v = red[tid] + red[tid + 128];
    if (bs < 32)
      S_red[b * 4096 + bs * 128 + tid] = v;
    else
      Z_red[b * 128 + tid] = v;
  }
}

// ---------------- kernel 2b: ctx = S/Z; T = Wo*ctx; W_eff = SCALE*T*Wq ----------------
__global__ void k2b_weff(const float* __restrict__ S_red, const float* __restrict__ Z_red,
                         const float* __restrict__ Wq, const float* __restrict__ Wo,
                         float* __restrict__ W_eff) {
  int b = blockIdx.x >> 3, og = blockIdx.x & 7;
  int tid = threadIdx.x;
  __shared__ float ctx_lds[4096];  // [h][d][e]
  __shared__ float T_lds[16 * 128];
  for (int i = tid * 16; i < tid * 16 + 16; ++i) {
    int h = i >> 10, d = (i >> 5) & 31, e = i & 31;
    int fl = h * 1024 + (((d >> 4) * 2 + (e >> 4)) << 8) + (((d >> 2) & 3) << 6) +
             ((e & 15) << 2) + (d & 3);
    ctx_lds[i] = S_red[b * 4096 + fl] / Z_red[b * 128 + h * 32 + d];
  }
  __syncthreads();
  {
    int o_loc = tid >> 4, hd0 = (tid & 15) * 8;
    int o = og * 16 + o_loc;
    for (int j = 0; j < 8; ++j) {
      int hd = hd0 + j, h = hd >> 5, d = hd & 31;
      const float* wo = Wo + o * 128 + h * 32;
      const float* cx = ctx_lds + h * 1024 + d * 32;
      float acc = 0.f;
      for (int e = 0; e < 32; ++e) acc += wo[e] * cx[e];
      T_lds[o_loc * 128 + hd] = acc;
    }
  }
  __syncthreads();
  {
    int o_loc = tid >> 4, c0 = (tid & 15) * 8;
    float acc[8] = {};
    const float* Trow = T_lds + o_loc * 128;
    for (int hd = 0; hd < 128; ++hd) {
      float tv = Trow[hd];
      const float* wq = Wq + hd * 128 + c0;
#pragma unroll
      for (int j = 0; j < 8; ++j) acc[j] += tv * wq[j];
    }
    float* op = W_eff + b * 16384 + (og * 16 + o_loc) * 128 + c0;
#pragma unroll
    for (int j = 0; j < 8; ++j) op[j] = F_SCALE * acc[j];
  }
}

// ---------------- kernel 3: out = W_eff[b] @ x[b] + bo (barrier-free) ----------------
// grid 512 = 4 b x 128 chunks of 512 n; wave w owns 128 n = 8 strips of 16.
// Per strip: pack->T2, MFMA m=8 (all 128 output rows), store-transpose via Dt.
__global__ __launch_bounds__(256, 2) void k3_out(const float* __restrict__ x,
                                                 const float* __restrict__ W_eff,
                                                 const float* __restrict__ bo,
                                                 float* __restrict__ out) {
  __shared__ char smem[32 * 1024];  // 8KB per wave: Dt 8K, T2 aliases first 4K
  const int tid = threadIdx.x;
  const int lane = tid & 63;
  const int w = tid >> 6;
  const int l15 = lane & 15;
  const int lg = lane >> 4;
  const int b = blockIdx.x >> 7;
  const int cb = blockIdx.x & 127;

  char* T2 = smem + w * 8192;
  char* Dt = smem + w * 8192;  // alias: Dt writes come after last T2 read (same-wave order)

  bf16x8 Wf[8][4];
#pragma unroll
  for (int m = 0; m < 8; ++m) {
    int o = m * 16 + l15;
#pragma unroll
    for (int ks = 0; ks < 4; ++ks) {
      const float* p = W_eff + b * 16384 + o * 128 + ks * 32 + lg * 8;
#pragma unroll
      for (int e = 0; e < 8; ++e) Wf[m][ks][e] = (__bf16)p[e];
    }
  }
  float bof[8];
#pragma unroll
  for (int m = 0; m < 8; ++m) bof[m] = bo[m * 16 + l15];

  const float* src = x + (size_t)b * CD * NTOK + cb * 512 + w * 128;
  float* dst = out + (size_t)b * CD * NTOK + cb * 512 + w * 128;

  Frag f = load_strip(src, lane);
#pragma unroll
  for (int s = 0; s < 8; ++s) {
    Frag fn;
    if (s < 7) fn = load_strip(src + (s + 1) * 16, lane);
    pack_write(f, T2, lane);

    f32x4 acc[8];
#pragma unroll
    for (int m = 0; m < 8; ++m) acc[m] = f32x4{0.f, 0.f, 0.f, 0.f};
#pragma unroll
    for (int ks = 0; ks < 4; ++ks) {
      bf16x8 At = *(const bf16x8*)(T2 + l15 * 256 + ((ks * 64 + lg * 16) ^ ((l15 & 7) << 4)));
#pragma unroll
      for (int m = 0; m < 8; ++m) acc[m] = MFMA16(At, Wf[m][ks], acc[m]);
    }

    // Dt [128 o][16 n] f32, swizzle phys = logical ^ (((o>>1)&3)<<4): 2-way both sides
#pragma unroll
    for (int m = 0; m < 8; ++m) {
      int o = m * 16 + l15;
      f32x4 v = acc[m];
      v[0] += bof[m]; v[1] += bof[m]; v[2] += bof[m]; v[3] += bof[m];
      *(f32x4*)(Dt + o * 64 + ((lg * 16) ^ (((o >> 1) & 3) << 4))) = v;
    }
#pragma unroll
    for (int i = 0; i < 8; ++i) {
      int o2 = i * 16 + (lane >> 2);
      int nq = lane & 3;
      f32x4 v = *(const f32x4*)(Dt + o2 * 64 + ((nq * 16) ^ (((o2 >> 1) & 3) << 4)));
      *(f32x4*)(dst + (size_t)o2 * NTOK + s * 16 + nq * 4) = v;
    }
    if (s < 7) f = fn;
  }
}

extern "C" void kernel_launch(void* const* d_in, const int* in_sizes, int n_in,
                              void* d_out, int out_size, void* d_ws, size_t ws_size,
                              hipStream_t stream) {
  const float* x = (const float*)d_in[0];
  const float* ctxg = (const float*)d_in[1];
  const float* Wq = (const float*)d_in[2];
  const float* Wk = (const float*)d_in[3];
  const float* Wv = (const float*)d_in[4];
  const float* Wo = (const float*)d_in[5];
  const float* bo = (const float*)d_in[6];
  float* out = (float*)d_out;

  float* ws = (float*)d_ws;
  float* S_part = ws;                         // 512 * 4224 floats
  float* S_red = ws + (size_t)512 * PART;     // 16384
  float* Z_red = S_red + 16384;               // 512
  float* W_eff = Z_red + 512;                 // 65536

  k1_ctx<<<dim3(512), dim3(256), 0, stream>>>(ctxg, Wk, Wv, S_part);
  k2a_reduce<<<dim3(132), dim3(256), 0, stream>>>(S_part, S_red, Z_red);
  k2b_weff<<<dim3(32), dim3(256), 0, stream>>>(S_red, Z_red, Wq, Wo, W_eff);
  k3_out<<<dim3(512), dim3(256), 0, stream>>>(x, W_eff, bo, out);
}

// Round 5
// 168.690 us; speedup vs baseline: 1.4235x; 1.4235x over previous
//
#include <hip/hip_runtime.h>
#include <cstdint>
#include <cstddef>

typedef __bf16 bf16x8 __attribute__((ext_vector_type(8)));
typedef float f32x4 __attribute__((ext_vector_type(4)));
typedef unsigned int u32x2 __attribute__((ext_vector_type(2)));

#define MFMA16(a, b, c) __builtin_amdgcn_mfma_f32_16x16x32_bf16((a), (b), (c), 0, 0, 0)

static constexpr int CD = 128;
static constexpr int NTOK = 65536;
static constexpr float F_SCALE = 0.17677669529663688f;  // 1/sqrt(32)
static constexpr float F_LOG2E = 1.4426950408889634f;
static constexpr int PART = 4224;    // 4096 S + 128 Z floats per k1 block
static constexpr int NPARTS = 128;   // k1 blocks per batch

__device__ __forceinline__ unsigned pk2(float a, float b) {
  unsigned short ua = __builtin_bit_cast(unsigned short, (__bf16)a);
  unsigned short ub = __builtin_bit_cast(unsigned short, (__bf16)b);
  return (unsigned)ua | ((unsigned)ub << 16);
}

// One "group" = [16 c rows][64 n] fp32. Lane holds 4 CONSECUTIVE c rows
// (4r..4r+3) x 4 n ((lane&15)*4..+3). Each load instr: 16 lanes x 16B = 256B
// contiguous per row (full 128B lines), 4 rows per instr.
struct Grp { f32x4 M[4]; };

__device__ __forceinline__ Grp load_grp(const float* src, int lane) {
  Grp g;
  const float* p = src + (size_t)((lane >> 4) * 4) * NTOK + (lane & 15) * 4;
#pragma unroll
  for (int v = 0; v < 4; ++v) g.M[v] = *(const f32x4*)(p + (size_t)v * NTOK);
  return g;
}

// Pack lane's 4 consecutive c at each of 4 n into c-quad b64 writes to
// T2 [64 n][128 c] bf16, swizzle: phys_byte = logical ^ ((n&7)<<4).
// (16B-granule XOR; b64 chunks keep their bit3, so b128 reads stay coherent.)
__device__ __forceinline__ void pack_grp(const Grp& g, char* T2, int cqBase, int lane) {
  int cq = cqBase + (lane >> 4);
  int nq = lane & 15;
#pragma unroll
  for (int j = 0; j < 4; ++j) {
    int n = nq * 4 + j;
    *(u32x2*)(T2 + n * 256 + ((cq * 8) ^ ((n & 7) << 4))) =
        u32x2{pk2(g.M[0][j], g.M[1][j]), pk2(g.M[2][j], g.M[3][j])};
  }
}

// ---------------- kernel 1: context -> S,Z partials ----------------
// grid 512 = 4 b x 128 chunks of 512 n, strips of 64 n. Wave w stages c-rows
// [w*32, w*32+32) x 64 n into shared T2 (dbuf, ONE barrier/strip); wave w
// computes head w over all 64 n. E/V tiles + S-MFMA wave-private.
__global__ __launch_bounds__(256, 2) void k1_ctx(
    const float* __restrict__ ctx_in, const float* __restrict__ Wk,
    const float* __restrict__ Wv, float* __restrict__ S_part) {
  __shared__ char smem[64 * 1024];  // T2[2] 2x16KB | per-wave E 4K + V 4K
  const int tid = threadIdx.x;
  const int lane = tid & 63;
  const int w = tid >> 6;
  const int l15 = lane & 15;
  const int lg = lane >> 4;
  const int b = blockIdx.x >> 7;
  const int cb = blockIdx.x & 127;

  char* Eb = smem + 32 * 1024 + w * 8192;
  char* Vb = Eb + 4096;

  // Weight B-fragments for head w: col = weight row = w*32 + (m&1)*16 + l15,
  // k = c = ks*32 + lg*8 + e. m=0,1 -> Wk (prescaled by log2e); m=2,3 -> Wv.
  bf16x8 Wf[4][4];
#pragma unroll
  for (int m = 0; m < 4; ++m) {
    const float* Wp = (m < 2) ? Wk : Wv;
    const float sc = (m < 2) ? F_LOG2E : 1.0f;
    int row = w * 32 + (m & 1) * 16 + l15;
#pragma unroll
    for (int ks = 0; ks < 4; ++ks) {
      const float* p = Wp + row * CD + ks * 32 + lg * 8;
#pragma unroll
      for (int e = 0; e < 8; ++e) Wf[m][ks][e] = (__bf16)(p[e] * sc);
    }
  }

  f32x4 Sacc[2][2];
#pragma unroll
  for (int i = 0; i < 2; ++i)
#pragma unroll
    for (int j = 0; j < 2; ++j) Sacc[i][j] = f32x4{0.f, 0.f, 0.f, 0.f};
  float zacc[2] = {0.f, 0.f};

  // Wave w stages c-rows [w*32, +16) and [w*32+16, +16) (two groups).
  const float* srcA = ctx_in + (size_t)b * CD * NTOK + (size_t)(w * 32) * NTOK + cb * 512;
  const float* srcB = srcA + (size_t)16 * NTOK;

  Grp fa = load_grp(srcA, lane), fb = load_grp(srcB, lane);
#pragma unroll
  for (int s = 0; s < 8; ++s) {
    char* T2 = smem + (s & 1) * 16384;
    pack_grp(fa, T2, w * 8, lane);
    pack_grp(fb, T2, w * 8 + 4, lane);
    Grp na, nb;
    if (s < 7) {  // prefetch next strip under barrier + compute
      na = load_grp(srcA + (s + 1) * 64, lane);
      nb = load_grp(srcB + (s + 1) * 64, lane);
    }
    __syncthreads();  // T2[s&1] complete (and prior compute on it done)

    // projections: D[n][wrow], n = t*16 + lg*4 + r, wrow col = l15
    f32x4 acc[4][4];
#pragma unroll
    for (int m = 0; m < 4; ++m)
#pragma unroll
      for (int t = 0; t < 4; ++t) acc[m][t] = f32x4{0.f, 0.f, 0.f, 0.f};
#pragma unroll
    for (int ks = 0; ks < 4; ++ks) {
      bf16x8 At[4];
#pragma unroll
      for (int t = 0; t < 4; ++t)
        At[t] = *(const bf16x8*)(T2 + (t * 16 + l15) * 256 +
                                 ((ks * 64 + lg * 16) ^ ((l15 & 7) << 4)));
#pragma unroll
      for (int m = 0; m < 4; ++m)
#pragma unroll
        for (int t = 0; t < 4; ++t) acc[m][t] = MFMA16(At[t], Wf[m][ks], acc[m][t]);
    }

    // exp + packed E/V into wave-private [32 d][64 n] bf16 tiles (2-way swz)
#pragma unroll
    for (int m = 0; m < 2; ++m) {
      int d = m * 16 + l15;
      int dx = (d & 7) << 4;
#pragma unroll
      for (int t = 0; t < 4; ++t) {
        f32x4 a = acc[m][t];
        float e0 = __builtin_exp2f(a[0]), e1 = __builtin_exp2f(a[1]);
        float e2 = __builtin_exp2f(a[2]), e3 = __builtin_exp2f(a[3]);
        zacc[m] += (e0 + e1) + (e2 + e3);
        *(u32x2*)(Eb + d * 128 + ((t * 32 + lg * 8) ^ dx)) =
            u32x2{pk2(e0, e1), pk2(e2, e3)};
        f32x4 v = acc[m + 2][t];
        *(u32x2*)(Vb + d * 128 + ((t * 32 + lg * 8) ^ dx)) =
            u32x2{pk2(v[0], v[1]), pk2(v[2], v[3])};
      }
    }

    // S[d][e] += E[d][n] * V[e][n], K = 64 (wave-private, no barrier)
#pragma unroll
    for (int s2 = 0; s2 < 2; ++s2) {
      bf16x8 Ea[2], Vv[2];
#pragma unroll
      for (int md = 0; md < 2; ++md) {
        int d = md * 16 + l15;
        int off = d * 128 + ((s2 * 64 + lg * 16) ^ ((d & 7) << 4));
        Ea[md] = *(const bf16x8*)(Eb + off);
        Vv[md] = *(const bf16x8*)(Vb + off);
      }
#pragma unroll
      for (int md = 0; md < 2; ++md)
#pragma unroll
        for (int ne = 0; ne < 2; ++ne) Sacc[md][ne] = MFMA16(Ea[md], Vv[ne], Sacc[md][ne]);
    }
    fa = na;
    fb = nb;
  }

  // Lane-linear partial writes (coalesced b128); mapping (used by k2b):
  // value (d = md*16+lg*4+r, e = ne*16+l15) at flat w*1024 + (md*2+ne)*256 + lane*4 + r
  float* outp = S_part + (size_t)blockIdx.x * PART;
#pragma unroll
  for (int md = 0; md < 2; ++md)
#pragma unroll
    for (int ne = 0; ne < 2; ++ne)
      *(f32x4*)(outp + w * 1024 + (md * 2 + ne) * 256 + lane * 4) = Sacc[md][ne];
#pragma unroll
  for (int m = 0; m < 2; ++m) {
    float z = zacc[m];
    z += __shfl_xor(z, 16, 64);
    z += __shfl_xor(z, 32, 64);
    if (lg == 0) outp[4096 + w * 32 + m * 16 + l15] = z;  // Z[h=w][d=m*16+l15]
  }
}

// ---------------- kernel 2a: reduce partials ----------------
__global__ void k2a_reduce(const float* __restrict__ S_part, float* __restrict__ S_red,
                           float* __restrict__ Z_red) {
  int bid = blockIdx.x;
  int b = bid / 33, bs = bid % 33;
  int tid = threadIdx.x;
  __shared__ float red[256];
  int e_loc = tid & 127, half = tid >> 7;
  const float* base =
      S_part + (size_t)b * NPARTS * PART + (bs < 32 ? bs * 128 + e_loc : 4096 + e_loc);
  float sum = 0.f;
  int h = NPARTS >> 1;
  for (int p = half * h; p < half * h + h; ++p) sum += base[(size_t)p * PART];
  red[tid] = sum;
  __syncthreads();
  if (tid < 128) {
    float v = red[tid] + red[tid + 128];
    if (bs < 32)
      S_red[b * 4096 + bs * 128 + tid] = v;
    else
      Z_red[b * 128 + tid] = v;
  }
}

// ---------------- kernel 2b: ctx = S/Z; T = Wo*ctx; W_eff = SCALE*T*Wq ----------------
__global__ void k2b_weff(const float* __restrict__ S_red, const float* __restrict__ Z_red,
                         const float* __restrict__ Wq, const float* __restrict__ Wo,
                         float* __restrict__ W_eff) {
  int b = blockIdx.x >> 3, og = blockIdx.x & 7;
  int tid = threadIdx.x;
  __shared__ float ctx_lds[4096];  // [h][d][e]
  __shared__ float T_lds[16 * 128];
  for (int i = tid * 16; i < tid * 16 + 16; ++i) {
    int h = i >> 10, d = (i >> 5) & 31, e = i & 31;
    int fl = h * 1024 + (((d >> 4) * 2 + (e >> 4)) << 8) + (((d >> 2) & 3) << 6) +
             ((e & 15) << 2) + (d & 3);
    ctx_lds[i] = S_red[b * 4096 + fl] / Z_red[b * 128 + h * 32 + d];
  }
  __syncthreads();
  {
    int o_loc = tid >> 4, hd0 = (tid & 15) * 8;
    int o = og * 16 + o_loc;
    for (int j = 0; j < 8; ++j) {
      int hd = hd0 + j, h = hd >> 5, d = hd & 31;
      const float* wo = Wo + o * 128 + h * 32;
      const float* cx = ctx_lds + h * 1024 + d * 32;
      float acc = 0.f;
      for (int e = 0; e < 32; ++e) acc += wo[e] * cx[e];
      T_lds[o_loc * 128 + hd] = acc;
    }
  }
  __syncthreads();
  {
    int o_loc = tid >> 4, c0 = (tid & 15) * 8;
    float acc[8] = {};
    const float* Trow = T_lds + o_loc * 128;
    for (int hd = 0; hd < 128; ++hd) {
      float tv = Trow[hd];
      const float* wq = Wq + hd * 128 + c0;
#pragma unroll
      for (int j = 0; j < 8; ++j) acc[j] += tv * wq[j];
    }
    float* op = W_eff + b * 16384 + (og * 16 + o_loc) * 128 + c0;
#pragma unroll
    for (int j = 0; j < 8; ++j) op[j] = F_SCALE * acc[j];
  }
}

// ---------------- kernel 3: out = W_eff[b] @ x[b] + bo ----------------
// grid 1024 = 4 b x 256 chunks of 256 n, 4 strips of 64 n. Block-cooperative:
// waves stage by c (256B/row loads) into shared T2 (dbuf, one barrier/strip);
// wave w computes o in [w*32, +32) x 64 n; stores 4x16B back-to-back per row
// (256B contiguous region) -> full-line writeback.
__global__ __launch_bounds__(256, 3) void k3_out(const float* __restrict__ x,
                                                 const float* __restrict__ W_eff,
                                                 const float* __restrict__ bo,
                                                 float* __restrict__ out) {
  __shared__ char smem[32 * 1024];  // T2 dbuf 2x16KB
  const int tid = threadIdx.x;
  const int lane = tid & 63;
  const int w = tid >> 6;
  const int l15 = lane & 15;
  const int lg = lane >> 4;
  const int b = blockIdx.x >> 8;
  const int cb = blockIdx.x & 255;

  bf16x8 Wf[2][4];
#pragma unroll
  for (int m = 0; m < 2; ++m) {
    int o = w * 32 + m * 16 + l15;
#pragma unroll
    for (int ks = 0; ks < 4; ++ks) {
      const float* p = W_eff + b * 16384 + o * 128 + ks * 32 + lg * 8;
#pragma unroll
      for (int e = 0; e < 8; ++e) Wf[m][ks][e] = (__bf16)p[e];
    }
  }
  float bof[2] = {bo[w * 32 + l15], bo[w * 32 + 16 + l15]};

  const float* srcA = x + (size_t)b * CD * NTOK + (size_t)(w * 32) * NTOK + cb * 256;
  const float* srcB = srcA + (size_t)16 * NTOK;
  float* dst = out + (size_t)b * CD * NTOK + cb * 256;

  Grp fa = load_grp(srcA, lane), fb = load_grp(srcB, lane);
#pragma unroll
  for (int s = 0; s < 4; ++s) {
    char* T2 = smem + (s & 1) * 16384;
    pack_grp(fa, T2, w * 8, lane);
    pack_grp(fb, T2, w * 8 + 4, lane);
    Grp na, nb;
    if (s < 3) {
      na = load_grp(srcA + (s + 1) * 64, lane);
      nb = load_grp(srcB + (s + 1) * 64, lane);
    }
    __syncthreads();

    f32x4 acc[2][4];
#pragma unroll
    for (int m = 0; m < 2; ++m)
#pragma unroll
      for (int t = 0; t < 4; ++t) acc[m][t] = f32x4{0.f, 0.f, 0.f, 0.f};
#pragma unroll
    for (int ks = 0; ks < 4; ++ks) {
      bf16x8 At[4];
#pragma unroll
      for (int t = 0; t < 4; ++t)
        At[t] = *(const bf16x8*)(T2 + (t * 16 + l15) * 256 +
                                 ((ks * 64 + lg * 16) ^ ((l15 & 7) << 4)));
#pragma unroll
      for (int m = 0; m < 2; ++m)
#pragma unroll
        for (int t = 0; t < 4; ++t) acc[m][t] = MFMA16(At[t], Wf[m][ks], acc[m][t]);
    }

    // store: D[n][o] -> for fixed o row, 4 stores (t=0..3) cover 256B region
#pragma unroll
    for (int m = 0; m < 2; ++m) {
      int o = w * 32 + m * 16 + l15;
      float bb = bof[m];
      float* drow = dst + (size_t)o * NTOK + s * 64 + lg * 4;
#pragma unroll
      for (int t = 0; t < 4; ++t) {
        f32x4 v = acc[m][t];
        v[0] += bb; v[1] += bb; v[2] += bb; v[3] += bb;
        *(f32x4*)(drow + t * 16) = v;
      }
    }
    fa = na;
    fb = nb;
  }
}

extern "C" void kernel_launch(void* const* d_in, const int* in_sizes, int n_in,
                              void* d_out, int out_size, void* d_ws, size_t ws_size,
                              hipStream_t stream) {
  const float* x = (const float*)d_in[0];
  const float* ctxg = (const float*)d_in[1];
  const float* Wq = (const float*)d_in[2];
  const float* Wk = (const float*)d_in[3];
  const float* Wv = (const float*)d_in[4];
  const float* Wo = (const float*)d_in[5];
  const float* bo = (const float*)d_in[6];
  float* out = (float*)d_out;

  float* ws = (float*)d_ws;
  float* S_part = ws;                         // 512 * 4224 floats
  float* S_red = ws + (size_t)512 * PART;     // 16384
  float* Z_red = S_red + 16384;               // 512
  float* W_eff = Z_red + 512;                 // 65536

  k1_ctx<<<dim3(512), dim3(256), 0, stream>>>(ctxg, Wk, Wv, S_part);
  k2a_reduce<<<dim3(132), dim3(256), 0, stream>>>(S_part, S_red, Z_red);
  k2b_weff<<<dim3(32), dim3(256), 0, stream>>>(S_red, Z_red, Wq, Wo, W_eff);
  k3_out<<<dim3(1024), dim3(256), 0, stream>>>(x, W_eff, bo, out);
}